// Round 4
// baseline (629.923 us; speedup 1.0000x reference)
//
#include <hip/hip_runtime.h>
#include <hip/hip_bf16.h>

// ---------------------------------------------------------------------------
// AttentionBase: out = softmax((in@Wq^T+bq)*ds @ (mem@Wk^T+bk)^T) @ (mem@Wv^T+bv) @ Wo^T + bo
// B=8, S=2048, C=1024.
// 256x256 tile, BK=64, 8 waves (2Mx4N), double-buffered 2-phase K-loop.
// T2 LDS swizzle: LDS stays LINEAR for global_load_lds; the st-style XOR
// (granule ^= row&7, 16B granules) is realized by permuting the per-lane
// GLOBAL source column at stage time and applying the same XOR on ds_read
// addresses (rule #21 both-sides). Read conflicts: 16-way -> 2-way (free).
// T1 chunked XCD swizzle on the flattened grid (all grids %8 == 0).
// PV row-sums via ones-operand MFMA (no separate pass).
// ---------------------------------------------------------------------------

typedef __attribute__((ext_vector_type(8))) short short8;   // 8 bf16 = 4 VGPRs
typedef __attribute__((ext_vector_type(4))) float f32x4;

static __device__ __forceinline__ unsigned short f2bf(float f) {
  union { float f; unsigned u; } x; x.f = f;
  unsigned r = x.u + 0x7FFFu + ((x.u >> 16) & 1u);   // round-to-nearest-even
  return (unsigned short)(r >> 16);
}

static __device__ __forceinline__ void g2l16(const void* g, void* l) {
  __builtin_amdgcn_global_load_lds(
      (const __attribute__((address_space(1))) void*)g,
      (__attribute__((address_space(3))) void*)l, 16, 0, 0);
}

// f32 -> bf16 conversion (weights), float4/ushort4 vectorized, grid-stride
__global__ __launch_bounds__(256) void cvt_kernel(const float* __restrict__ in,
                                                  unsigned short* __restrict__ out,
                                                  long long n4) {
  long long i = (long long)blockIdx.x * 256 + threadIdx.x;
  const long long stride = (long long)gridDim.x * 256;
  for (; i < n4; i += stride) {
    float4 v = ((const float4*)in)[i];
    ushort4 o;
    o.x = f2bf(v.x); o.y = f2bf(v.y); o.z = f2bf(v.z); o.w = f2bf(v.w);
    ((ushort4*)out)[i] = o;
  }
}

// ---------------------------------------------------------------------------
// gemm: D[m][n] = epilogue(sum_k A[m][k]*B[n][k] (+bias[n]) (*scale))
// EPI: 0=bf16 (bias+scale)  1=bf16 transposed store D[n][m]
//      2=bf16 exp(acc)      3=bf16 acc/rowsum (PV)      4=f32 (bias)
// ---------------------------------------------------------------------------
#define EPI_BF16 0
#define EPI_BF16_TRANS 1
#define EPI_EXP 2
#define EPI_PV 3
#define EPI_F32 4

template <bool A_F32, int EPI, bool HAS_BIAS>
__global__ __launch_bounds__(512, 2) void gemm_kernel(
    const void* __restrict__ Av, const unsigned short* __restrict__ B,
    const float* __restrict__ bias, void* __restrict__ Dv,
    int K, int lda, int ldb, int ldd,
    long long sA, long long sB, long long sD, float scale) {
  // ---- T1: chunked XCD swizzle over the flattened grid (nwg % 8 == 0) ----
  int lin = blockIdx.x + gridDim.x * (blockIdx.y + gridDim.y * blockIdx.z);
  const int nwg = gridDim.x * gridDim.y * gridDim.z;
  lin = (lin & 7) * (nwg >> 3) + (lin >> 3);
  const int bx = lin % gridDim.x;
  int rem = lin / gridDim.x;
  const int by = rem % gridDim.y;
  const int bz = rem / gridDim.y;

  const int bm = bx * 256;
  const int bn = by * 256;
  const int tid = threadIdx.x;
  const int lane = tid & 63;
  const int wid = tid >> 6;
  const int wr = (wid >> 2) * 128;   // wave row offset (2 rows of waves)
  const int wc = (wid & 3) * 64;     // wave col offset (4 cols of waves)
  const int fr = lane & 15;
  const int hi = lane >> 4;

  __shared__ __align__(16) unsigned short As[2][256 * 64];
  __shared__ __align__(16) unsigned short Bs[2][256 * 64];

  f32x4 acc[8][4];
#pragma unroll
  for (int m = 0; m < 8; ++m)
#pragma unroll
    for (int n = 0; n < 4; ++n) acc[m][n] = (f32x4){0.f, 0.f, 0.f, 0.f};

  f32x4 asum[8];          // PV: row-sums via ones-operand MFMA
  short8 ones;
#pragma unroll
  for (int m = 0; m < 8; ++m) asum[m] = (f32x4){0.f, 0.f, 0.f, 0.f};
#pragma unroll
  for (int j = 0; j < 8; ++j) ones[j] = (short)0x3F80;  // bf16 1.0

  // ---- staging addressing: thread tid fills linear LDS slot (i*512+tid),
  //      i.e. row = i*64 + (tid>>3), linear granule tid&7. Source granule is
  //      XOR-permuted so reads can apply the same XOR (T2 both-sides). ----
  const int srow = tid >> 3;                    // 0..63
  const int sgr  = (tid & 7) ^ (srow & 7);      // permuted source granule
  const unsigned short* Bp = B + (long long)bz * sB + (long long)(bn + srow) * ldb + sgr * 8;
  const unsigned short* Ab =
      A_F32 ? nullptr
            : (const unsigned short*)Av + (long long)bz * sA + (long long)(bm + srow) * lda + sgr * 8;
  const float* Af =
      A_F32 ? (const float*)Av + (long long)bz * sA + (long long)(bm + srow) * lda + sgr * 8
            : nullptr;

  const int NT = K >> 6;

  // ---- prologue: stage K-tile 0 into buf 0 ----
  {
    float4 ua[8];
    if (A_F32) {
#pragma unroll
      for (int i = 0; i < 4; ++i) {
        const float* src = Af + (long long)(i * 64) * lda;
        ua[2 * i]     = ((const float4*)src)[0];
        ua[2 * i + 1] = ((const float4*)src)[1];
      }
    } else {
#pragma unroll
      for (int i = 0; i < 4; ++i)
        g2l16(Ab + (long long)(i * 64) * lda, &As[0][(i * 512 + tid) * 8]);
    }
#pragma unroll
    for (int i = 0; i < 4; ++i)
      g2l16(Bp + (long long)(i * 64) * ldb, &Bs[0][(i * 512 + tid) * 8]);
    if (A_F32) {
#pragma unroll
      for (int i = 0; i < 4; ++i) {
        short8 pk;
        pk[0] = (short)f2bf(ua[2*i].x); pk[1] = (short)f2bf(ua[2*i].y);
        pk[2] = (short)f2bf(ua[2*i].z); pk[3] = (short)f2bf(ua[2*i].w);
        pk[4] = (short)f2bf(ua[2*i+1].x); pk[5] = (short)f2bf(ua[2*i+1].y);
        pk[6] = (short)f2bf(ua[2*i+1].z); pk[7] = (short)f2bf(ua[2*i+1].w);
        *(short8*)&As[0][(i * 512 + tid) * 8] = pk;
      }
    }
  }
  __syncthreads();

  int cur = 0;
  for (int t = 0; t < NT; ++t) {
    const int k1 = (t + 1) << 6;
    const bool pf = (t + 1 < NT);
    float4 ua[8];
    // ---- issue prefetch of K-tile t+1 into buf cur^1 (before compute) ----
    if (pf) {
      if (A_F32) {
#pragma unroll
        for (int i = 0; i < 4; ++i) {
          const float* src = Af + (long long)(i * 64) * lda + k1;
          ua[2 * i]     = ((const float4*)src)[0];
          ua[2 * i + 1] = ((const float4*)src)[1];
        }
      } else {
#pragma unroll
        for (int i = 0; i < 4; ++i)
          g2l16(Ab + (long long)(i * 64) * lda + k1, &As[cur ^ 1][(i * 512 + tid) * 8]);
      }
#pragma unroll
      for (int i = 0; i < 4; ++i)
        g2l16(Bp + (long long)(i * 64) * ldb + k1, &Bs[cur ^ 1][(i * 512 + tid) * 8]);
    }
    // ---- compute K-tile t from buf cur (swizzled ds_read, 2-way max) ----
#pragma unroll
    for (int kk = 0; kk < 2; ++kk) {
      short8 af[8], bf[4];
#pragma unroll
      for (int m = 0; m < 8; ++m) {
        const int row = wr + m * 16 + fr;
        af[m] = *(const short8*)&As[cur][(row << 6) + ((((kk << 2) + hi) ^ (fr & 7)) << 3)];
      }
#pragma unroll
      for (int n = 0; n < 4; ++n) {
        const int row = wc + n * 16 + fr;
        bf[n] = *(const short8*)&Bs[cur][(row << 6) + ((((kk << 2) + hi) ^ (fr & 7)) << 3)];
      }
#pragma unroll
      for (int m = 0; m < 8; ++m)
#pragma unroll
        for (int n = 0; n < 4; ++n)
          acc[m][n] = __builtin_amdgcn_mfma_f32_16x16x32_bf16(af[m], bf[n],
                                                              acc[m][n], 0, 0, 0);
      if (EPI == EPI_PV) {
#pragma unroll
        for (int m = 0; m < 8; ++m)
          asum[m] = __builtin_amdgcn_mfma_f32_16x16x32_bf16(af[m], ones,
                                                            asum[m], 0, 0, 0);
      }
    }
    // ---- A_F32: convert + linear ds_write of the prefetched tile ----
    if (pf && A_F32) {
#pragma unroll
      for (int i = 0; i < 4; ++i) {
        short8 pk;
        pk[0] = (short)f2bf(ua[2*i].x); pk[1] = (short)f2bf(ua[2*i].y);
        pk[2] = (short)f2bf(ua[2*i].z); pk[3] = (short)f2bf(ua[2*i].w);
        pk[4] = (short)f2bf(ua[2*i+1].x); pk[5] = (short)f2bf(ua[2*i+1].y);
        pk[6] = (short)f2bf(ua[2*i+1].z); pk[7] = (short)f2bf(ua[2*i+1].w);
        *(short8*)&As[cur ^ 1][(i * 512 + tid) * 8] = pk;
      }
    }
    __syncthreads();
    cur ^= 1;
  }

  // ---- epilogue: C/D frag layout col=lane&15, row=(lane>>4)*4+j ----
  const int cr = hi * 4;
  const int cc = fr;
#pragma unroll
  for (int m = 0; m < 8; ++m) {
    const int row0 = bm + wr + m * 16 + cr;
#pragma unroll
    for (int n = 0; n < 4; ++n) {
      const int col = bn + wc + n * 16 + cc;
      const float bv = HAS_BIAS ? bias[col] : 0.f;
      if (EPI == EPI_F32) {
        float* D = (float*)Dv + (long long)bz * sD;
#pragma unroll
        for (int j = 0; j < 4; ++j)
          D[(long long)(row0 + j) * ldd + col] = acc[m][n][j] + bv;
      } else if (EPI == EPI_BF16) {
        unsigned short* D = (unsigned short*)Dv + (long long)bz * sD;
#pragma unroll
        for (int j = 0; j < 4; ++j)
          D[(long long)(row0 + j) * ldd + col] = f2bf((acc[m][n][j] + bv) * scale);
      } else if (EPI == EPI_BF16_TRANS) {
        unsigned short* D = (unsigned short*)Dv + (long long)bz * sD;
        ushort4 pk;
        pk.x = f2bf((acc[m][n][0] + bv) * scale);
        pk.y = f2bf((acc[m][n][1] + bv) * scale);
        pk.z = f2bf((acc[m][n][2] + bv) * scale);
        pk.w = f2bf((acc[m][n][3] + bv) * scale);
        *(ushort4*)&D[(long long)col * ldd + row0] = pk;
      } else if (EPI == EPI_EXP) {
        unsigned short* D = (unsigned short*)Dv + (long long)bz * sD;
#pragma unroll
        for (int j = 0; j < 4; ++j)
          D[(long long)(row0 + j) * ldd + col] = f2bf(__expf(acc[m][n][j]));
      } else {  // EPI_PV: normalize by MFMA-computed row-sum
        unsigned short* D = (unsigned short*)Dv + (long long)bz * sD;
#pragma unroll
        for (int j = 0; j < 4; ++j) {
          const float li = 1.f / asum[m][j];
          D[(long long)(row0 + j) * ldd + col] = f2bf(acc[m][n][j] * li);
        }
      }
    }
  }
}

extern "C" void kernel_launch(void* const* d_in, const int* in_sizes, int n_in,
                              void* d_out, int out_size, void* d_ws, size_t ws_size,
                              hipStream_t stream) {
  (void)in_sizes; (void)n_in; (void)out_size;
  const float* input  = (const float*)d_in[0];
  const float* memory = (const float*)d_in[1];
  const float* Wq = (const float*)d_in[2];
  const float* bq = (const float*)d_in[3];
  const float* Wk = (const float*)d_in[4];
  const float* bk = (const float*)d_in[5];
  const float* Wv = (const float*)d_in[6];
  const float* bv = (const float*)d_in[7];
  const float* Wo = (const float*)d_in[8];
  const float* bo = (const float*)d_in[9];
  float* out = (float*)d_out;

  const int S = 2048, C = 1024;
  const int CB = 2;                                // batches per attention chunk
  const long long BS = 16384;                      // 8 * 2048
  const long long N_IN = BS * C;                   // 16,777,216
  const long long N_W  = (long long)C * C;         // 1,048,576

  // ---- workspace layout (256B aligned regions), ~120 MiB total ----
  char* p = (char*)d_ws;
  auto alloc = [&](size_t bytes) {
    char* r = p;
    p += (bytes + 255) & ~(size_t)255;
    return r;
  };
  unsigned short* wqb  = (unsigned short*)alloc(N_W * 2);
  unsigned short* wkb  = (unsigned short*)alloc(N_W * 2);
  unsigned short* wvb  = (unsigned short*)alloc(N_W * 2);
  unsigned short* wob  = (unsigned short*)alloc(N_W * 2);
  unsigned short* Qb   = (unsigned short*)alloc(N_IN * 2);   // [16384][1024]; later sel
  unsigned short* Kb   = (unsigned short*)alloc(N_IN * 2);   // [16384][1024]
  unsigned short* Vt   = (unsigned short*)alloc(N_IN * 2);   // [1024][16384]
  unsigned short* Pt   = (unsigned short*)alloc((long long)CB * S * S * 2);  // [CB*2048][2048]
  if ((size_t)(p - (char*)d_ws) > ws_size) return;

  // ---- weight f32 -> bf16 ----
  cvt_kernel<<<1024, 256, 0, stream>>>(Wq, wqb, N_W / 4);
  cvt_kernel<<<1024, 256, 0, stream>>>(Wk, wkb, N_W / 4);
  cvt_kernel<<<1024, 256, 0, stream>>>(Wv, wvb, N_W / 4);
  cvt_kernel<<<1024, 256, 0, stream>>>(Wo, wob, N_W / 4);

  const float depth_scale = 0.03125f;  // 1024^-0.5

  // ---- projections (A = f32 input/memory, converted in staging) ----
  gemm_kernel<true, EPI_BF16, true><<<dim3(64, 4, 1), 512, 0, stream>>>(
      input, wqb, bq, Qb, C, C, C, C, 0, 0, 0, depth_scale);
  gemm_kernel<true, EPI_BF16, true><<<dim3(64, 4, 1), 512, 0, stream>>>(
      memory, wkb, bk, Kb, C, C, C, C, 0, 0, 0, 1.0f);
  gemm_kernel<true, EPI_BF16_TRANS, true><<<dim3(64, 4, 1), 512, 0, stream>>>(
      memory, wvb, bv, Vt, C, C, C, (int)BS, 0, 0, 0, 1.0f);

  // ---- attention, CB batches at a time ----
  for (int c = 0; c < 8 / CB; ++c) {
    const long long qoff = (long long)c * CB * S * C;
    // P~ = exp(Q[b] @ K[b]^T) -> bf16 [CB*2048][2048]
    gemm_kernel<false, EPI_EXP, false><<<dim3(8, 8, CB), 512, 0, stream>>>(
        Qb + qoff, Kb + qoff, nullptr, Pt,
        C, C, C, S, (long long)S * C, (long long)S * C, (long long)S * S, 1.0f);
    // sel[b] = (P~ @ V[b]) / rowsum(P~)  -> bf16, aliasing dead Q rows
    gemm_kernel<false, EPI_PV, false><<<dim3(8, 4, CB), 512, 0, stream>>>(
        Pt, Vt + (long long)c * CB * S, nullptr, Qb + qoff,
        S, S, (int)BS, C, (long long)S * S, (long long)S, (long long)S * C, 1.0f);
  }

  // ---- out = sel @ Wo^T + bo -> f32 [16384][1024] ----
  gemm_kernel<false, EPI_F32, true><<<dim3(64, 4, 1), 512, 0, stream>>>(
      Qb, wob, bo, out, C, C, C, C, 0, 0, 0, 1.0f);
}

// Round 5
// 460.038 us; speedup vs baseline: 1.3693x; 1.3693x over previous
//
#include <hip/hip_runtime.h>
#include <hip/hip_bf16.h>

// ---------------------------------------------------------------------------
// AttentionBase: out = softmax((in@Wq^T+bq)*ds @ (mem@Wk^T+bk)^T) @ (mem@Wv^T+bv) @ Wo^T + bo
// B=8, S=2048, C=1024. All matmuls bf16 MFMA gemm_bt.
// Quad-buffered BK=32 K-pipeline (T3/T4): per iter
//   [vmcnt(2*LT) counted wait] [s_barrier] [stage tile t+3] [ds_read+MFMA t] [s_barrier]
// Loads for 2 future tiles stay in flight across barriers; vmcnt never drains
// to 0 in steady state. Stage(t+3) writes the buffer freed 2 barriers ago.
// Granule swizzle (g ^= (row>>1)&3, 16B granules) applied on BOTH sides:
// pre-swizzled global source for global_load_lds (linear LDS dst) + swizzled
// ds_read address -> 2-way bank conflicts (free).
// d_out is used as scratch: [Vt bf16 | input-bf16] before the final out-proj
// overwrites it. Pt (CB=4 chunk of exp-scores) aliases dead memb.
// ---------------------------------------------------------------------------

typedef __attribute__((ext_vector_type(8))) short short8;   // 8 bf16 = 4 VGPRs
typedef __attribute__((ext_vector_type(4))) float f32x4;

static __device__ __forceinline__ unsigned short f2bf(float f) {
  union { float f; unsigned u; } x; x.f = f;
  unsigned r = x.u + 0x7FFFu + ((x.u >> 16) & 1u);   // round-to-nearest-even
  return (unsigned short)(r >> 16);
}

static __device__ __forceinline__ void g2l16(const void* g, void* l) {
  __builtin_amdgcn_global_load_lds(
      (const __attribute__((address_space(1))) void*)g,
      (__attribute__((address_space(3))) void*)l, 16, 0, 0);
}

// f32 -> bf16 conversion, float4/ushort4 vectorized, grid-stride
__global__ __launch_bounds__(256) void cvt_kernel(const float* __restrict__ in,
                                                  unsigned short* __restrict__ out,
                                                  long long n4) {
  long long i = (long long)blockIdx.x * 256 + threadIdx.x;
  const long long stride = (long long)gridDim.x * 256;
  for (; i < n4; i += stride) {
    float4 v = ((const float4*)in)[i];
    ushort4 o;
    o.x = f2bf(v.x); o.y = f2bf(v.y); o.z = f2bf(v.z); o.w = f2bf(v.w);
    ((ushort4*)out)[i] = o;
  }
}

#define EPI_BF16 0
#define EPI_BF16_TRANS 1
#define EPI_EXP 2
#define EPI_PV 3
#define EPI_F32 4

// D[m][n] = epilogue(sum_k A[m][k]*B[n][k] (+bias[n]) (*scale)), batched via z.
template <int BM, int BN, int WM, int WN, int EPI, bool HAS_BIAS>
__global__ __launch_bounds__(512, 2) void gemm_kernel(
    const unsigned short* __restrict__ A, const unsigned short* __restrict__ B,
    const float* __restrict__ bias, void* __restrict__ Dv,
    int K, int lda, int ldb, int ldd,
    long long sA, long long sB, long long sD, float scale) {
  constexpr int MF = BM / (WM * 16);   // m-frags per wave
  constexpr int NF = BN / (WN * 16);   // n-frags per wave
  constexpr int LA = BM / 128;         // g2l16 per thread per A K-slice
  constexpr int LB = BN / 128;         // g2l16 per thread per B K-slice
  constexpr int LT = LA + LB;

  // ---- T1: chunked XCD swizzle over the flattened grid (nwg % 8 == 0) ----
  int lin = blockIdx.x + gridDim.x * (blockIdx.y + gridDim.y * blockIdx.z);
  const int nwg = gridDim.x * gridDim.y * gridDim.z;
  lin = (lin & 7) * (nwg >> 3) + (lin >> 3);
  const int bx = lin % gridDim.x;
  int rem0 = lin / gridDim.x;
  const int by = rem0 % gridDim.y;
  const int bz = rem0 / gridDim.y;

  const int bm = bx * BM;
  const int bn = by * BN;
  const int tid = threadIdx.x;
  const int lane = tid & 63;
  const int wid = tid >> 6;
  const int wr = (wid / WN) * (BM / WM);
  const int wc = (wid % WN) * (BN / WN);
  const int fr = lane & 15;
  const int hi = lane >> 4;

  __shared__ __align__(16) unsigned short As[4][BM * 32];
  __shared__ __align__(16) unsigned short Bs[4][BN * 32];

  f32x4 acc[MF][NF];
#pragma unroll
  for (int m = 0; m < MF; ++m)
#pragma unroll
    for (int n = 0; n < NF; ++n) acc[m][n] = (f32x4){0.f, 0.f, 0.f, 0.f};

  f32x4 asum[MF];          // PV: row-sums via ones-operand MFMA
  short8 ones;
#pragma unroll
  for (int m = 0; m < MF; ++m) asum[m] = (f32x4){0.f, 0.f, 0.f, 0.f};
#pragma unroll
  for (int j = 0; j < 8; ++j) ones[j] = (short)0x3F80;  // bf16 1.0

  const unsigned short* Abase = A + (long long)bz * sA;
  const unsigned short* Bbase = B + (long long)bz * sB;

  // stage K-slice tt (32 k) into buf tt&3: linear LDS dst, swizzled source
  auto stage = [&](int tt) {
    const int buf = tt & 3;
#pragma unroll
    for (int i = 0; i < LA; ++i) {
      const int slot = i * 512 + tid;
      const int row = slot >> 2;
      const int gs = (slot & 3) ^ ((row >> 1) & 3);
      g2l16(Abase + (long long)(bm + row) * lda + tt * 32 + gs * 8,
            &As[buf][slot * 8]);
    }
#pragma unroll
    for (int i = 0; i < LB; ++i) {
      const int slot = i * 512 + tid;
      const int row = slot >> 2;
      const int gs = (slot & 3) ^ ((row >> 1) & 3);
      g2l16(Bbase + (long long)(bn + row) * ldb + tt * 32 + gs * 8,
            &Bs[buf][slot * 8]);
    }
  };

  const int NT = K >> 5;   // K-slices of 32

  // prologue: fill the pipeline 3 deep
  stage(0); stage(1); stage(2);

  // lane-constant read-granule xor: ((row>>1)&3) == ((fr>>1)&3) since all
  // other row terms are multiples of 16
  const int glx = (fr >> 1) & 3;

  for (int t = 0; t < NT; ++t) {
    const int ahead = NT - 1 - t;   // future tiles already issued: min(2, ahead)
    if (ahead >= 2) {
      if (LT == 4) asm volatile("s_waitcnt vmcnt(8)" ::: "memory");
      else         asm volatile("s_waitcnt vmcnt(6)" ::: "memory");
    } else if (ahead == 1) {
      if (LT == 4) asm volatile("s_waitcnt vmcnt(4)" ::: "memory");
      else         asm volatile("s_waitcnt vmcnt(3)" ::: "memory");
    } else {
      asm volatile("s_waitcnt vmcnt(0)" ::: "memory");
    }
    __builtin_amdgcn_s_barrier();
    __builtin_amdgcn_sched_barrier(0);   // no ds_read may hoist above barrier

    if (t + 3 < NT) stage(t + 3);        // writes buf freed 2 barriers ago

    const int buf = t & 3;
    short8 af[MF], bf[NF];
#pragma unroll
    for (int m = 0; m < MF; ++m) {
      const int row = wr + m * 16 + fr;
      af[m] = *(const short8*)&As[buf][row * 32 + ((hi ^ glx) << 3)];
    }
#pragma unroll
    for (int n = 0; n < NF; ++n) {
      const int row = wc + n * 16 + fr;
      bf[n] = *(const short8*)&Bs[buf][row * 32 + ((hi ^ glx) << 3)];
    }
#pragma unroll
    for (int m = 0; m < MF; ++m)
#pragma unroll
      for (int n = 0; n < NF; ++n)
        acc[m][n] = __builtin_amdgcn_mfma_f32_16x16x32_bf16(af[m], bf[n],
                                                            acc[m][n], 0, 0, 0);
    if (EPI == EPI_PV) {
#pragma unroll
      for (int m = 0; m < MF; ++m)
        asum[m] = __builtin_amdgcn_mfma_f32_16x16x32_bf16(af[m], ones,
                                                          asum[m], 0, 0, 0);
    }
    __builtin_amdgcn_sched_barrier(0);   // no ds_read may sink below barrier
    __builtin_amdgcn_s_barrier();
  }

  // ---- epilogue: C/D frag layout col=lane&15, row=(lane>>4)*4+j ----
  const int cr = hi * 4;
  const int cc = fr;
#pragma unroll
  for (int m = 0; m < MF; ++m) {
    const int row0 = bm + wr + m * 16 + cr;
#pragma unroll
    for (int n = 0; n < NF; ++n) {
      const int col = bn + wc + n * 16 + cc;
      const float bv = HAS_BIAS ? bias[col] : 0.f;
      if (EPI == EPI_F32) {
        float* D = (float*)Dv + (long long)bz * sD;
#pragma unroll
        for (int j = 0; j < 4; ++j)
          D[(long long)(row0 + j) * ldd + col] = acc[m][n][j] + bv;
      } else if (EPI == EPI_BF16) {
        unsigned short* D = (unsigned short*)Dv + (long long)bz * sD;
#pragma unroll
        for (int j = 0; j < 4; ++j)
          D[(long long)(row0 + j) * ldd + col] = f2bf((acc[m][n][j] + bv) * scale);
      } else if (EPI == EPI_BF16_TRANS) {
        unsigned short* D = (unsigned short*)Dv + (long long)bz * sD;
        ushort4 pk;
        pk.x = f2bf((acc[m][n][0] + bv) * scale);
        pk.y = f2bf((acc[m][n][1] + bv) * scale);
        pk.z = f2bf((acc[m][n][2] + bv) * scale);
        pk.w = f2bf((acc[m][n][3] + bv) * scale);
        *(ushort4*)&D[(long long)col * ldd + row0] = pk;
      } else if (EPI == EPI_EXP) {
        unsigned short* D = (unsigned short*)Dv + (long long)bz * sD;
#pragma unroll
        for (int j = 0; j < 4; ++j)
          D[(long long)(row0 + j) * ldd + col] = f2bf(__expf(acc[m][n][j]));
      } else {  // EPI_PV: normalize by MFMA-computed row-sum
        unsigned short* D = (unsigned short*)Dv + (long long)bz * sD;
#pragma unroll
        for (int j = 0; j < 4; ++j) {
          const float li = 1.f / asum[m][j];
          D[(long long)(row0 + j) * ldd + col] = f2bf(acc[m][n][j] * li);
        }
      }
    }
  }
}

extern "C" void kernel_launch(void* const* d_in, const int* in_sizes, int n_in,
                              void* d_out, int out_size, void* d_ws, size_t ws_size,
                              hipStream_t stream) {
  (void)in_sizes; (void)n_in; (void)out_size;
  const float* input  = (const float*)d_in[0];
  const float* memory = (const float*)d_in[1];
  const float* Wq = (const float*)d_in[2];
  const float* bq = (const float*)d_in[3];
  const float* Wk = (const float*)d_in[4];
  const float* bk = (const float*)d_in[5];
  const float* Wv = (const float*)d_in[6];
  const float* bv = (const float*)d_in[7];
  const float* Wo = (const float*)d_in[8];
  const float* bo = (const float*)d_in[9];
  float* out = (float*)d_out;

  const int S = 2048, C = 1024;
  const int CB = 4;                                // batches per attention chunk
  const long long BS = 16384;                      // 8 * 2048
  const long long N_IN = BS * C;                   // 16,777,216
  const long long N_W  = (long long)C * C;         // 1,048,576

  // ---- workspace layout (256B aligned), ~109 MiB ----
  char* p = (char*)d_ws;
  auto alloc = [&](size_t bytes) {
    char* r = p;
    p += (bytes + 255) & ~(size_t)255;
    return r;
  };
  unsigned short* wqb  = (unsigned short*)alloc(N_W * 2);
  unsigned short* wkb  = (unsigned short*)alloc(N_W * 2);
  unsigned short* wvb  = (unsigned short*)alloc(N_W * 2);
  unsigned short* wob  = (unsigned short*)alloc(N_W * 2);
  unsigned short* Qb   = (unsigned short*)alloc(N_IN * 2);   // [16384][1024]; later sel
  unsigned short* Kb   = (unsigned short*)alloc(N_IN * 2);   // [16384][1024]
  unsigned short* Xb   = (unsigned short*)alloc(N_IN * 2);   // memb, then Pt (CB*S*S=N_IN)
  if ((size_t)(p - (char*)d_ws) > ws_size) return;

  // d_out scratch: [Vt bf16 16M elems | inb bf16 16M elems] = exactly 64 MiB
  unsigned short* Vt  = (unsigned short*)d_out;          // [1024][16384]
  unsigned short* inb = (unsigned short*)d_out + N_IN;   // [16384][1024]
  unsigned short* memb = Xb;
  unsigned short* Pt   = Xb;                             // alias after memb dead

  // ---- f32 -> bf16 ----
  cvt_kernel<<<1024, 256, 0, stream>>>(Wq, wqb, N_W / 4);
  cvt_kernel<<<1024, 256, 0, stream>>>(Wk, wkb, N_W / 4);
  cvt_kernel<<<1024, 256, 0, stream>>>(Wv, wvb, N_W / 4);
  cvt_kernel<<<1024, 256, 0, stream>>>(Wo, wob, N_W / 4);
  cvt_kernel<<<2048, 256, 0, stream>>>(memory, memb, N_IN / 4);
  cvt_kernel<<<2048, 256, 0, stream>>>(input,  inb,  N_IN / 4);

  const float depth_scale = 0.03125f;  // 1024^-0.5

  // ---- projections: grid 256 blocks (1/CU), 512 thr ----
  // K = mem @ Wk^T + bk
  gemm_kernel<256, 256, 2, 4, EPI_BF16, true><<<dim3(64, 4, 1), 512, 0, stream>>>(
      memb, wkb, bk, Kb, C, C, C, C, 0, 0, 0, 1.0f);
  // Vt = (mem @ Wv^T + bv)^T  -> d_out lo half
  gemm_kernel<256, 256, 2, 4, EPI_BF16_TRANS, true><<<dim3(64, 4, 1), 512, 0, stream>>>(
      memb, wvb, bv, Vt, C, C, C, (int)BS, 0, 0, 0, 1.0f);
  // Q = (in @ Wq^T + bq) * ds   (A = inb in d_out hi half)
  gemm_kernel<256, 256, 2, 4, EPI_BF16, true><<<dim3(64, 4, 1), 512, 0, stream>>>(
      inb, wqb, bq, Qb, C, C, C, C, 0, 0, 0, depth_scale);

  // ---- attention, CB=4 batches at a time (memb dead -> Pt) ----
  for (int c = 0; c < 8 / CB; ++c) {
    const long long qoff = (long long)c * CB * S * C;
    // P~ = exp(Q[b] @ K[b]^T) -> bf16 [CB*2048][2048], grid (8,8,4)=256
    gemm_kernel<256, 256, 2, 4, EPI_EXP, false><<<dim3(8, 8, CB), 512, 0, stream>>>(
        Qb + qoff, Kb + qoff, nullptr, Pt,
        C, C, C, S, (long long)S * C, (long long)S * C, (long long)S * S, 1.0f);
    // sel[b] = (P~ @ V[b]) / rowsum(P~) -> bf16 over dead Q rows, grid (8,8,4)=256
    gemm_kernel<256, 128, 4, 2, EPI_PV, false><<<dim3(8, 8, CB), 512, 0, stream>>>(
        Pt, Vt + (long long)c * CB * S, nullptr, Qb + qoff,
        S, S, (int)BS, C, (long long)S * S, (long long)S, (long long)S * C, 1.0f);
  }

  // ---- out = sel @ Wo^T + bo -> f32 d_out (overwrites Vt/inb scratch) ----
  gemm_kernel<256, 256, 2, 4, EPI_F32, true><<<dim3(64, 4, 1), 512, 0, stream>>>(
      Qb, wob, bo, out, C, C, C, C, 0, 0, 0, 1.0f);
}